// Round 5
// baseline (274.915 us; speedup 1.0000x reference)
//
#include <hip/hip_runtime.h>
#include <math.h>

#define NH 16
#define HDIM 64
#define D_ATTN 1024
#define KW 4
#define ATT_SCALE 0.125f
#define LKV_C 512
#define LQ_C 4096
#define B_C 4

typedef _Float16 f16;
typedef _Float16 f16x8 __attribute__((ext_vector_type(8)));
typedef _Float16 f16x4 __attribute__((ext_vector_type(4)));
typedef _Float16 f16x2 __attribute__((ext_vector_type(2)));
typedef float f32x4 __attribute__((ext_vector_type(4)));

typedef __attribute__((address_space(3))) unsigned int as3_uint;
typedef __attribute__((address_space(1))) const unsigned int as1_uint;

__device__ __forceinline__ void gld_lds16(const f16* g, f16* l) {
    __builtin_amdgcn_global_load_lds((as1_uint*)g, (as3_uint*)l, 16, 0, 0);
}

// fp16 4-element dot with fp32 accumulate (v_dot2_f32_f16 when available)
__device__ __forceinline__ float dot4_f16(f16x4 a, f16x4 b) {
#if __has_builtin(__builtin_amdgcn_fdot2)
    f16x2 alo = {a.x, a.y}, ahi = {a.z, a.w};
    f16x2 blo = {b.x, b.y}, bhi = {b.z, b.w};
    float p = __builtin_amdgcn_fdot2(alo, blo, 0.f, false);
    return __builtin_amdgcn_fdot2(ahi, bhi, p, false);
#else
    return (float)a.x * (float)b.x + (float)a.y * (float)b.y +
           (float)a.z * (float)b.z + (float)a.w * (float)b.w;
#endif
}

// ---------------------------------------------------------------------------
// One-shot fp32 -> fp16 conversion of all five inputs (segment table in
// float4 units; grid covers exactly 5,767,168 float4s = 22528 blocks x 256).
// ---------------------------------------------------------------------------
#define SEG_Q   4194304          // 4*4096*1024/4
#define SEG_KV  (SEG_Q + 524288) // + 4*512*1024/4
#define SEG_WQ  (SEG_KV + 262144)
#define SEG_WKV (SEG_WQ + 524288)
#define SEG_END (SEG_WKV + 262144)

__global__ __launch_bounds__(256) void split_all(const float* __restrict__ q,
                                                 const float* __restrict__ kv,
                                                 const float* __restrict__ Wq,
                                                 const float* __restrict__ Wkv,
                                                 const float* __restrict__ Wo,
                                                 f16* __restrict__ q_hi,
                                                 f16* __restrict__ kvs_hi,
                                                 f16* __restrict__ Wq_hi,
                                                 f16* __restrict__ Wkv_hi,
                                                 f16* __restrict__ Wo_hi) {
    const int i = blockIdx.x * 256 + threadIdx.x;
    const float* src; f16* dst; int base;
    if (i < SEG_Q)        { src = q;   dst = q_hi;   base = 0; }
    else if (i < SEG_KV)  { src = kv;  dst = kvs_hi; base = SEG_Q; }
    else if (i < SEG_WQ)  { src = Wq;  dst = Wq_hi;  base = SEG_KV; }
    else if (i < SEG_WKV) { src = Wkv; dst = Wkv_hi; base = SEG_WQ; }
    else                  { src = Wo;  dst = Wo_hi;  base = SEG_WKV; }
    const int j = i - base;
    float4 v = ((const float4*)src)[j];
    ((f16x4*)dst)[j] = (f16x4){(f16)v.x, (f16)v.y, (f16)v.z, (f16)v.w};
}

// ---------------------------------------------------------------------------
// 128x128-tile GEMM (2-barrier structure) — kept for the kv projection
// (M=2048, N=2048: 256 blocks). Templated output type (fp32 or fp16).
// ---------------------------------------------------------------------------
template <typename OT>
__global__ __launch_bounds__(256) void gemm_f16(const f16* __restrict__ A,
                                                const f16* __restrict__ B,
                                                OT* __restrict__ C,
                                                int M, int N, int K) {
    __shared__ f16 smem[2 * 128 * 32];   // A | B, 16 KB
    f16* sA = smem;
    f16* sB = smem + 4096;

    const int t = threadIdx.x;
    const int w = t >> 6;
    const int lane = t & 63;
    const int bm = blockIdx.y * 128;
    const int bn = blockIdx.x * 128;
    const int wm = (w & 1) * 64;
    const int wn = (w >> 1) * 64;

    f32x4 acc[4][4] = {};

    const int frow = lane & 15;
    const int fchunk = lane >> 4;

    const int srow = t >> 2;
    const int chunk = (t & 3) ^ ((t >> 3) & 3);
    const size_t aoff0 = (size_t)(bm + srow) * K + chunk * 8;
    const size_t aoff1 = (size_t)(bm + 64 + srow) * K + chunk * 8;
    const size_t boff0 = (size_t)(bn + srow) * K + chunk * 8;
    const size_t boff1 = (size_t)(bn + 64 + srow) * K + chunk * 8;
    const unsigned loff0 = (w * 64) * 8;
    const unsigned loff1 = (256 + w * 64) * 8;

    gld_lds16(A + aoff0, sA + loff0);  gld_lds16(A + aoff1, sA + loff1);
    gld_lds16(B + boff0, sB + loff0);  gld_lds16(B + boff1, sB + loff1);

    for (int k0 = 0; k0 < K; k0 += 32) {
        __syncthreads();

        f16x8 a[4], b[4];
        #pragma unroll
        for (int i = 0; i < 4; ++i) {
            const int r = wm + i * 16 + frow;
            a[i] = *(const f16x8*)(sA + r * 32 + (fchunk ^ ((r >> 1) & 3)) * 8);
        }
        #pragma unroll
        for (int j = 0; j < 4; ++j) {
            const int r = wn + j * 16 + frow;
            b[j] = *(const f16x8*)(sB + r * 32 + (fchunk ^ ((r >> 1) & 3)) * 8);
        }

        __syncthreads();

        if (k0 + 32 < K) {
            const int kn = k0 + 32;
            gld_lds16(A + aoff0 + kn, sA + loff0);  gld_lds16(A + aoff1 + kn, sA + loff1);
            gld_lds16(B + boff0 + kn, sB + loff0);  gld_lds16(B + boff1 + kn, sB + loff1);
        }

        #pragma unroll
        for (int i = 0; i < 4; ++i)
            #pragma unroll
            for (int j = 0; j < 4; ++j)
                acc[i][j] = __builtin_amdgcn_mfma_f32_16x16x32_f16(a[i], b[j], acc[i][j], 0, 0, 0);
    }

    const int rbase = bm + wm + (lane >> 4) * 4;
    const int cbase = bn + wn + (lane & 15);
    #pragma unroll
    for (int i = 0; i < 4; ++i)
        #pragma unroll
        for (int j = 0; j < 4; ++j)
            #pragma unroll
            for (int r = 0; r < 4; ++r)
                C[(size_t)(rbase + i * 16 + r) * N + cbase + j * 16] = (OT)acc[i][j][r];
}

// ---------------------------------------------------------------------------
// 128x128-tile, BK=64, 4-phase, counted-vmcnt GEMM (C = A[M,K] @ B[N,K]^T).
// 2 blocks/CU (64 KiB LDS, 256 threads). See round-4 comments for the phase
// schedule and vmcnt accounting (unchanged).
//
// FUSE=true: instead of storing C = A@B^T (the qh tile), run the windowed
// attention on the 128-row x 2-head tile in the epilogue and store attn_o.
// Requires OT=f16, N=1024, kvp/seg_id non-null, kv projection already done.
// Attention is per-head independent, so a (row-block, 2-head) tile is
// self-contained: stash qh tile to LDS (pipeline LDS is dead after the
// K-loop), then each wave handles its 32 rows x 2 heads, gathering k/v from
// the L2-resident kvp.
// ---------------------------------------------------------------------------
__device__ __forceinline__ void stage64(const f16* __restrict__ g, size_t row0,
                                        int K, int kcol, f16* l) {
    const int t = threadIdx.x;
    #pragma unroll
    for (int i = 0; i < 2; ++i) {
        const int idx = i * 256 + t;                 // 512 x 16B = 64 rows x 64 cols
        const int r = idx >> 3;
        const int qg = (idx & 7) ^ (r & 7);          // inverse (= same) swizzle
        gld_lds16(g + (row0 + r) * (size_t)K + kcol + qg * 8, l + idx * 8);
    }
}

#define BAR __builtin_amdgcn_s_barrier()
#define VM6 asm volatile("s_waitcnt vmcnt(6)" ::: "memory")
#define VM8 asm volatile("s_waitcnt vmcnt(8)" ::: "memory")
#define VM0 asm volatile("s_waitcnt vmcnt(0)" ::: "memory")

#define RD_A(S, mh)                                                         \
    { _Pragma("unroll") for (int mi = 0; mi < 2; ++mi) {                    \
        const f16* p = (S) + ((mh) * 64 + mi * 32 + arow) * 64;             \
        a[0][mi] = *(const f16x8*)(p + q0);                                 \
        a[1][mi] = *(const f16x8*)(p + q1); } }

#define RD_B(S, nh)                                                         \
    { _Pragma("unroll") for (int ni = 0; ni < 2; ++ni) {                    \
        const f16* p = (S) + (((nh) * 2 + ni) * 32 + brow) * 64;            \
        b[0][(nh) * 2 + ni] = *(const f16x8*)(p + q0);                      \
        b[1][(nh) * 2 + ni] = *(const f16x8*)(p + q1); } }

#define QUAD(mh, nh)                                                        \
    { _Pragma("unroll") for (int mi = 0; mi < 2; ++mi)                      \
      _Pragma("unroll") for (int ni = 0; ni < 2; ++ni) {                    \
          f32x4& c = acc[(mh) * 2 + mi][(nh) * 2 + ni];                     \
          c = __builtin_amdgcn_mfma_f32_16x16x32_f16(a[0][mi], b[0][(nh) * 2 + ni], c, 0, 0, 0); \
          c = __builtin_amdgcn_mfma_f32_16x16x32_f16(a[1][mi], b[1][(nh) * 2 + ni], c, 0, 0, 0); \
      } }

#define QUAD2(mh)                                                           \
    { __builtin_amdgcn_s_setprio(1); QUAD(mh, 0); QUAD(mh, 1);              \
      __builtin_amdgcn_s_setprio(0); }

template <typename OT, bool FUSE>
__global__ __launch_bounds__(256, 2) void gemm128(const f16* __restrict__ A,
                                                  const f16* __restrict__ B,
                                                  OT* __restrict__ C,
                                                  int M, int N, int K,
                                                  const f16* __restrict__ kvp,
                                                  const int* __restrict__ seg_id) {
    __shared__ __align__(16) f16 smem[4 * 8192];    // 64 KiB: A0|A1|B0|B1
    f16* const sA0 = smem;
    f16* const sA1 = smem + 8192;
    f16* const sB0 = smem + 16384;
    f16* const sB1 = smem + 24576;

    const int t = threadIdx.x;
    const int lane = t & 63;
    const int w = t >> 6;
    const int wr = w >> 1;                // 0..1 (M)
    const int wc = w & 1;                 // 0..1 (N)
    const int frow = lane & 15;
    const int fc = lane >> 4;

    // XCD-aware bijective swizzle (grid size is a multiple of 8)
    const int nbx = N >> 7;
    const int nwg = gridDim.x;
    const int wg = (blockIdx.x & 7) * (nwg >> 3) + (blockIdx.x >> 3);
    const int bm = (wg / nbx) << 7;
    const int bn = (wg % nbx) << 7;

    const int arow = wr * 16 + frow;      // + mh*64 + mi*32 (interleaved rows)
    const int brow = wc * 16 + frow;      // + (nh*2+ni)*32
    const int q0 = (fc ^ (frow & 7)) * 8;        // swizzled chunk, kstep 0
    const int q1 = ((4 + fc) ^ (frow & 7)) * 8;  // swizzled chunk, kstep 1

    f32x4 acc[4][4] = {};
    f16x8 a[2][2], b[2][4];

    // prologue: stage K-tiles 0 (buf0) and 1 (buf1)
    stage64(A, bm,      K, 0,  sA0);
    stage64(A, bm + 64, K, 0,  sA0 + 4096);
    stage64(B, bn,      K, 0,  sB0);
    stage64(B, bn + 64, K, 0,  sB0 + 4096);
    stage64(A, bm,      K, 64, sA1);
    stage64(A, bm + 64, K, 64, sA1 + 4096);
    stage64(B, bn,      K, 64, sB1);
    stage64(B, bn + 64, K, 64, sB1 + 4096);
    VM8;                                   // K-tile 0 landed (tile 1 in flight)
    BAR;

    const int NT = K >> 7;                 // 2 K-tiles (of 64) per iteration
    for (int it = 0; it < NT; ++it) {
        const bool lastit = (it == NT - 1);
        const int kc1 = (it * 2 + 1) << 6;
        const int kc2 = (it * 2 + 2) << 6;
        const int kc3 = (it * 2 + 3) << 6;

        // phA: consume buf0-h0 rows x all B of buf0; restage A1-h1 (tile 2it+1)
        RD_A(sA0, 0); RD_B(sB0, 0); RD_B(sB0, 1);
        if (it > 0) stage64(A, bm + 64, K, kc1, sA1 + 4096);
        BAR; QUAD2(0); BAR;

        // phB: consume buf0-h1 rows; restage buf0 (tile 2it+2) except A-h1
        RD_A(sA0, 1);
        if (!lastit) {
            stage64(A, bm,      K, kc2, sA0);
            stage64(B, bn,      K, kc2, sB0);
            stage64(B, bn + 64, K, kc2, sB0 + 4096);
            VM6;                           // tile 2it+1 fully landed
        } else {
            VM0;
        }
        BAR; QUAD2(1); BAR;

        // phC: consume buf1-h0 rows x all B of buf1; restage A0-h1 (kc2)
        RD_A(sA1, 0); RD_B(sB1, 0); RD_B(sB1, 1);
        if (!lastit) stage64(A, bm + 64, K, kc2, sA0 + 4096);
        BAR; QUAD2(0); BAR;

        // phD: consume buf1-h1 rows; restage buf1 (tile 2it+3) except A-h1
        RD_A(sA1, 1);
        if (!lastit) {
            stage64(A, bm,      K, kc3, sA1);
            stage64(B, bn,      K, kc3, sB1);
            stage64(B, bn + 64, K, kc3, sB1 + 4096);
            VM6;                           // tile 2it+2 fully landed
        }
        BAR; QUAD2(1); BAR;
    }

    if constexpr (!FUSE) {
        // epilogue: C/D layout col = lane&15, row = (lane>>4)*4 + reg
        const size_t rb = (size_t)bm + wr * 16 + ((lane >> 4) << 2);
        const int cb = bn + wc * 16 + (lane & 15);
        #pragma unroll
        for (int m = 0; m < 4; ++m)
            #pragma unroll
            for (int n = 0; n < 4; ++n)
                #pragma unroll
                for (int rr = 0; rr < 4; ++rr)
                    C[(rb + (m >> 1) * 64 + (m & 1) * 32 + rr) * N + cb + n * 32] =
                        (OT)acc[m][n][rr];
    } else {
        // ------------------- fused windowed attention epilogue -------------
        // 1) stash qh tile (f16, [128][128]) into the now-dead pipeline LDS
        f16* const sQ = smem;               // 32 KB
        __syncthreads();
        const int lrb = wr * 16 + ((lane >> 4) << 2);
        const int lcb = wc * 16 + (lane & 15);
        #pragma unroll
        for (int m = 0; m < 4; ++m)
            #pragma unroll
            for (int n = 0; n < 4; ++n)
                #pragma unroll
                for (int rr = 0; rr < 4; ++rr)
                    sQ[(lrb + (m >> 1) * 64 + (m & 1) * 32 + rr) * 128 + lcb + n * 32] =
                        (f16)acc[m][n][rr];
        __syncthreads();

        // 2) wave w handles local rows [32w, 32w+32), both heads of this tile.
        //    lanes: sub = row parity, hh2 = head within pair, s = dim quad
        const int sub = lane >> 5;
        const int lcol = ((lane >> 4) & 1) * 64 + (lane & 15) * 4;  // col in tile
        const int bb = bm >> 12;            // batch (4096 rows per batch)
        const f16* kvb = kvp + (size_t)bb * LKV_C * (2 * D_ATTN);
        f16* const Cf = (f16*)C;

        for (int t4 = 0; t4 < 4; ++t4) {
            int rl[4], sg[4];
            f16x4 qv[4];
            #pragma unroll
            for (int u = 0; u < 4; ++u) {
                rl[u] = (w << 5) + ((t4 * 4 + u) << 1) + sub;
                sg[u] = seg_id[bm + rl[u]];
                qv[u] = *(const f16x4*)(sQ + rl[u] * 128 + lcol);
            }
            float sc[4][KW];
            #pragma unroll
            for (int u = 0; u < 4; ++u)
                #pragma unroll
                for (int wk = 0; wk < KW; ++wk) {
                    const int j = sg[u] - wk;
                    float p = 0.f;
                    if (j >= 0) {
                        f16x4 k4 = *(const f16x4*)(kvb + (size_t)j * (2 * D_ATTN) + bn + lcol);
                        p = dot4_f16(qv[u], k4);
                    }
                    sc[u][wk] = p;
                }
            #pragma unroll
            for (int u = 0; u < 4; ++u)
                #pragma unroll
                for (int wk = 0; wk < KW; ++wk) {
                    float p = sc[u][wk];
                    p += __shfl_xor(p, 1);
                    p += __shfl_xor(p, 2);
                    p += __shfl_xor(p, 4);
                    p += __shfl_xor(p, 8);
                    sc[u][wk] = (sg[u] - wk >= 0) ? p * ATT_SCALE : -1e30f;
                }
            #pragma unroll
            for (int u = 0; u < 4; ++u) {
                const float mx = fmaxf(fmaxf(sc[u][0], sc[u][1]), fmaxf(sc[u][2], sc[u][3]));
                float e[KW], sum = 0.f;
                #pragma unroll
                for (int wk = 0; wk < KW; ++wk) {
                    e[wk] = __expf(sc[u][wk] - mx);
                    sum += e[wk];
                }
                const float inv = 1.f / sum;
                float ox = 0.f, oy = 0.f, oz = 0.f, ow = 0.f;
                #pragma unroll
                for (int wk = 0; wk < KW; ++wk) {
                    const int j = sg[u] - wk;
                    if (j >= 0) {
                        f16x4 v4 = *(const f16x4*)(kvb + (size_t)j * (2 * D_ATTN) + D_ATTN + bn + lcol);
                        const float c = e[wk] * inv;
                        ox = fmaf(c, (float)v4.x, ox);
                        oy = fmaf(c, (float)v4.y, oy);
                        oz = fmaf(c, (float)v4.z, oz);
                        ow = fmaf(c, (float)v4.w, ow);
                    }
                }
                *(f16x4*)(Cf + (size_t)(bm + rl[u]) * N + bn + lcol) =
                    (f16x4){(f16)ox, (f16)oy, (f16)oz, (f16)ow};
            }
        }
    }
}

// ---------------------------------------------------------------------------
// Standalone windowed attention (fallback path if workspace is too small for
// the fused layout). Same as round 4.
// ---------------------------------------------------------------------------
__global__ __launch_bounds__(256) void attn_kernel(const f16* __restrict__ qh,
                                                   const f16* __restrict__ kvp,
                                                   const int* __restrict__ seg_id,
                                                   f16* __restrict__ attn_o) {
    const int hg = threadIdx.x >> 6;
    const int lane = threadIdx.x & 63;
    const int r0 = blockIdx.x << 2;
    const int hh = lane >> 4;
    const int s  = lane & 15;
    const int dbase = (hg * 4 + hh) * HDIM + 4 * s;
    const int b = r0 >> 12;
    const f16* kvb = kvp + (size_t)b * LKV_C * (2 * D_ATTN);

    int seg[4];
    float4 q[4];
    #pragma unroll
    for (int i = 0; i < 4; ++i) {
        seg[i] = seg_id[r0 + i];
        f16x4 qv = *(const f16x4*)(qh + (size_t)(r0 + i) * D_ATTN + dbase);
        q[i] = make_float4((float)qv.x, (float)qv.y, (float)qv.z, (float)qv.w);
    }

    float sc[4][KW];
    #pragma unroll
    for (int i = 0; i < 4; ++i)
        #pragma unroll
        for (int w = 0; w < KW; ++w) {
            const int j = seg[i] - w;
            float p = 0.f;
            if (j >= 0) {
                f16x4 k4 = *(const f16x4*)(kvb + (size_t)j * (2 * D_ATTN) + dbase);
                p = q[i].x * (float)k4.x + q[i].y * (float)k4.y +
                    q[i].z * (float)k4.z + q[i].w * (float)k4.w;
            }
            sc[i][w] = p;
        }
    #pragma unroll
    for (int i = 0; i < 4; ++i)
        #pragma unroll
        for (int w = 0; w < KW; ++w) {
            float p = sc[i][w];
            p += __shfl_xor(p, 1);
            p += __shfl_xor(p, 2);
            p += __shfl_xor(p, 4);
            p += __shfl_xor(p, 8);
            sc[i][w] = (seg[i] - w >= 0) ? p * ATT_SCALE : -1e30f;
        }

    #pragma unroll
    for (int i = 0; i < 4; ++i) {
        const float m = fmaxf(fmaxf(sc[i][0], sc[i][1]), fmaxf(sc[i][2], sc[i][3]));
        float e[KW], sum = 0.f;
        #pragma unroll
        for (int w = 0; w < KW; ++w) {
            e[w] = __expf(sc[i][w] - m);
            sum += e[w];
        }
        const float inv = 1.f / sum;

        float4 o = make_float4(0.f, 0.f, 0.f, 0.f);
        #pragma unroll
        for (int w = 0; w < KW; ++w) {
            const int j = seg[i] - w;
            if (j >= 0) {
                f16x4 v4 = *(const f16x4*)(kvb + (size_t)j * (2 * D_ATTN) + D_ATTN + dbase);
                const float c = e[w] * inv;
                o.x = fmaf(c, (float)v4.x, o.x);
                o.y = fmaf(c, (float)v4.y, o.y);
                o.z = fmaf(c, (float)v4.z, o.z);
                o.w = fmaf(c, (float)v4.w, o.w);
            }
        }
        *(f16x4*)(attn_o + (size_t)(r0 + i) * D_ATTN + dbase) =
            (f16x4){(f16)o.x, (f16)o.y, (f16)o.z, (f16)o.w};
    }
}

extern "C" void kernel_launch(void* const* d_in, const int* in_sizes, int n_in,
                              void* d_out, int out_size, void* d_ws, size_t ws_size,
                              hipStream_t stream) {
    const float* q      = (const float*)d_in[0]; // (4,4096,1024)
    const float* kv_src = (const float*)d_in[1]; // (4,512,1024)
    const int*   seg    = (const int*)  d_in[2]; // (4,4096)
    const float* Wq     = (const float*)d_in[3]; // (1024,1024)
    const float* Wkv    = (const float*)d_in[4]; // (2048,1024)
    const float* Wo     = (const float*)d_in[5]; // (1024,1024)
    float* out = (float*)d_out;

    const int M  = B_C * LQ_C;    // 16384
    const int Mk = B_C * LKV_C;   // 2048

    // workspace layout
    f16* q_hi   = (f16*)d_ws;                       // 32 MB
    f16* kvs_hi = q_hi   + (size_t)M * D_ATTN;      // 4 MB
    f16* Wq_hi  = kvs_hi + (size_t)Mk * 1024;       // 2 MB
    f16* Wkv_hi = Wq_hi  + 1024 * 1024;             // 4 MB
    f16* Wo_hi  = Wkv_hi + 2048 * 1024;             // 2 MB
    f16* kvp    = Wo_hi  + 1024 * 1024;             // 8 MB (fp16 K|V)
    f16* attn_sep = kvp  + (size_t)Mk * 2048;       // 32 MB (fused path)

    const size_t need = (size_t)(attn_sep - (f16*)d_ws + (size_t)M * D_ATTN) * sizeof(f16);

    // 1. fp32 -> fp16 conversion of all inputs (single kernel)
    split_all<<<SEG_END / 256, 256, 0, stream>>>(q, kv_src, Wq, Wkv, Wo,
                                                 q_hi, kvs_hi, Wq_hi, Wkv_hi, Wo_hi);

    // 2. kvp = kv_src @ Wkv^T  (fp16) — must precede the fused attention
    gemm_f16<f16><<<dim3(2048 / 128, Mk / 128), 256, 0, stream>>>(kvs_hi, Wkv_hi, kvp, Mk, 2048, 1024);

    if (ws_size >= need) {
        // 3. fused: qh = q @ Wq^T computed per-tile, attention applied in
        //    epilogue, attn written directly (qh never materialized in HBM)
        gemm128<f16, true><<<(M / 128) * (1024 / 128), 256, 0, stream>>>(
            q_hi, Wq_hi, attn_sep, M, 1024, 1024, kvp, seg);
        // 4. out = attn @ Wo^T  (fp32)
        gemm128<float, false><<<(M / 128) * (1024 / 128), 256, 0, stream>>>(
            attn_sep, Wo_hi, out, M, 1024, 1024, nullptr, nullptr);
    } else {
        // fallback: round-4 five-kernel path (attn_o aliases q_hi)
        f16* attn_o = q_hi;
        f16* qh16   = (f16*)d_out;
        gemm128<f16, false><<<(M / 128) * (1024 / 128), 256, 0, stream>>>(
            q_hi, Wq_hi, qh16, M, 1024, 1024, nullptr, nullptr);
        attn_kernel<<<M / 4, 256, 0, stream>>>(qh16, kvp, seg, attn_o);
        gemm128<float, false><<<(M / 128) * (1024 / 128), 256, 0, stream>>>(
            attn_o, Wo_hi, out, M, 1024, 1024, nullptr, nullptr);
    }
}

// Round 6
// 259.217 us; speedup vs baseline: 1.0606x; 1.0606x over previous
//
#include <hip/hip_runtime.h>
#include <math.h>

#define NH 16
#define HDIM 64
#define D_ATTN 1024
#define KW 4
#define ATT_SCALE 0.125f
#define LKV_C 512
#define LQ_C 4096
#define B_C 4

typedef _Float16 f16;
typedef _Float16 f16x8 __attribute__((ext_vector_type(8)));
typedef _Float16 f16x4 __attribute__((ext_vector_type(4)));
typedef _Float16 f16x2 __attribute__((ext_vector_type(2)));
typedef float f32x4 __attribute__((ext_vector_type(4)));

typedef __attribute__((address_space(3))) unsigned int as3_uint;
typedef __attribute__((address_space(1))) const unsigned int as1_uint;

__device__ __forceinline__ void gld_lds16(const f16* g, f16* l) {
    __builtin_amdgcn_global_load_lds((as1_uint*)g, (as3_uint*)l, 16, 0, 0);
}

// fp16 4-element dot with fp32 accumulate (v_dot2_f32_f16 when available)
__device__ __forceinline__ float dot4_f16(f16x4 a, f16x4 b) {
#if __has_builtin(__builtin_amdgcn_fdot2)
    f16x2 alo = {a.x, a.y}, ahi = {a.z, a.w};
    f16x2 blo = {b.x, b.y}, bhi = {b.z, b.w};
    float p = __builtin_amdgcn_fdot2(alo, blo, 0.f, false);
    return __builtin_amdgcn_fdot2(ahi, bhi, p, false);
#else
    return (float)a.x * (float)b.x + (float)a.y * (float)b.y +
           (float)a.z * (float)b.z + (float)a.w * (float)b.w;
#endif
}

// ---------------------------------------------------------------------------
// One-shot fp32 -> fp16 conversion of all five inputs (segment table in
// float4 units; grid covers exactly 5,767,168 float4s = 22528 blocks x 256).
// ---------------------------------------------------------------------------
#define SEG_Q   4194304          // 4*4096*1024/4
#define SEG_KV  (SEG_Q + 524288) // + 4*512*1024/4
#define SEG_WQ  (SEG_KV + 262144)
#define SEG_WKV (SEG_WQ + 524288)
#define SEG_END (SEG_WKV + 262144)

__global__ __launch_bounds__(256) void split_all(const float* __restrict__ q,
                                                 const float* __restrict__ kv,
                                                 const float* __restrict__ Wq,
                                                 const float* __restrict__ Wkv,
                                                 const float* __restrict__ Wo,
                                                 f16* __restrict__ q_hi,
                                                 f16* __restrict__ kvs_hi,
                                                 f16* __restrict__ Wq_hi,
                                                 f16* __restrict__ Wkv_hi,
                                                 f16* __restrict__ Wo_hi) {
    const int i = blockIdx.x * 256 + threadIdx.x;
    const float* src; f16* dst; int base;
    if (i < SEG_Q)        { src = q;   dst = q_hi;   base = 0; }
    else if (i < SEG_KV)  { src = kv;  dst = kvs_hi; base = SEG_Q; }
    else if (i < SEG_WQ)  { src = Wq;  dst = Wq_hi;  base = SEG_KV; }
    else if (i < SEG_WKV) { src = Wkv; dst = Wkv_hi; base = SEG_WQ; }
    else                  { src = Wo;  dst = Wo_hi;  base = SEG_WKV; }
    const int j = i - base;
    float4 v = ((const float4*)src)[j];
    ((f16x4*)dst)[j] = (f16x4){(f16)v.x, (f16)v.y, (f16)v.z, (f16)v.w};
}

// ---------------------------------------------------------------------------
// 128x128-tile GEMM (2-barrier structure) — kept for the kv projection
// (M=2048, N=2048: 256 blocks). Templated output type (fp32 or fp16).
// ---------------------------------------------------------------------------
template <typename OT>
__global__ __launch_bounds__(256) void gemm_f16(const f16* __restrict__ A,
                                                const f16* __restrict__ B,
                                                OT* __restrict__ C,
                                                int M, int N, int K) {
    __shared__ f16 smem[2 * 128 * 32];   // A | B, 16 KB
    f16* sA = smem;
    f16* sB = smem + 4096;

    const int t = threadIdx.x;
    const int w = t >> 6;
    const int lane = t & 63;
    const int bm = blockIdx.y * 128;
    const int bn = blockIdx.x * 128;
    const int wm = (w & 1) * 64;
    const int wn = (w >> 1) * 64;

    f32x4 acc[4][4] = {};

    const int frow = lane & 15;
    const int fchunk = lane >> 4;

    const int srow = t >> 2;
    const int chunk = (t & 3) ^ ((t >> 3) & 3);
    const size_t aoff0 = (size_t)(bm + srow) * K + chunk * 8;
    const size_t aoff1 = (size_t)(bm + 64 + srow) * K + chunk * 8;
    const size_t boff0 = (size_t)(bn + srow) * K + chunk * 8;
    const size_t boff1 = (size_t)(bn + 64 + srow) * K + chunk * 8;
    const unsigned loff0 = (w * 64) * 8;
    const unsigned loff1 = (256 + w * 64) * 8;

    gld_lds16(A + aoff0, sA + loff0);  gld_lds16(A + aoff1, sA + loff1);
    gld_lds16(B + boff0, sB + loff0);  gld_lds16(B + boff1, sB + loff1);

    for (int k0 = 0; k0 < K; k0 += 32) {
        __syncthreads();

        f16x8 a[4], b[4];
        #pragma unroll
        for (int i = 0; i < 4; ++i) {
            const int r = wm + i * 16 + frow;
            a[i] = *(const f16x8*)(sA + r * 32 + (fchunk ^ ((r >> 1) & 3)) * 8);
        }
        #pragma unroll
        for (int j = 0; j < 4; ++j) {
            const int r = wn + j * 16 + frow;
            b[j] = *(const f16x8*)(sB + r * 32 + (fchunk ^ ((r >> 1) & 3)) * 8);
        }

        __syncthreads();

        if (k0 + 32 < K) {
            const int kn = k0 + 32;
            gld_lds16(A + aoff0 + kn, sA + loff0);  gld_lds16(A + aoff1 + kn, sA + loff1);
            gld_lds16(B + boff0 + kn, sB + loff0);  gld_lds16(B + boff1 + kn, sB + loff1);
        }

        #pragma unroll
        for (int i = 0; i < 4; ++i)
            #pragma unroll
            for (int j = 0; j < 4; ++j)
                acc[i][j] = __builtin_amdgcn_mfma_f32_16x16x32_f16(a[i], b[j], acc[i][j], 0, 0, 0);
    }

    const int rbase = bm + wm + (lane >> 4) * 4;
    const int cbase = bn + wn + (lane & 15);
    #pragma unroll
    for (int i = 0; i < 4; ++i)
        #pragma unroll
        for (int j = 0; j < 4; ++j)
            #pragma unroll
            for (int r = 0; r < 4; ++r)
                C[(size_t)(rbase + i * 16 + r) * N + cbase + j * 16] = (OT)acc[i][j][r];
}

// ---------------------------------------------------------------------------
// 128x128-tile, BK=64, 4-phase, counted-vmcnt GEMM (C = A[M,K] @ B[N,K]^T).
// 2 blocks/CU (64 KiB LDS, 256 threads). See round-4 comments for the phase
// schedule and vmcnt accounting (unchanged, un-fused — round-5 fusion
// regressed: LDS bank conflicts + serial tail at 1/4 the TLP).
// ---------------------------------------------------------------------------
__device__ __forceinline__ void stage64(const f16* __restrict__ g, size_t row0,
                                        int K, int kcol, f16* l) {
    const int t = threadIdx.x;
    #pragma unroll
    for (int i = 0; i < 2; ++i) {
        const int idx = i * 256 + t;                 // 512 x 16B = 64 rows x 64 cols
        const int r = idx >> 3;
        const int qg = (idx & 7) ^ (r & 7);          // inverse (= same) swizzle
        gld_lds16(g + (row0 + r) * (size_t)K + kcol + qg * 8, l + idx * 8);
    }
}

#define BAR __builtin_amdgcn_s_barrier()
#define VM6 asm volatile("s_waitcnt vmcnt(6)" ::: "memory")
#define VM8 asm volatile("s_waitcnt vmcnt(8)" ::: "memory")
#define VM0 asm volatile("s_waitcnt vmcnt(0)" ::: "memory")

#define RD_A(S, mh)                                                         \
    { _Pragma("unroll") for (int mi = 0; mi < 2; ++mi) {                    \
        const f16* p = (S) + ((mh) * 64 + mi * 32 + arow) * 64;             \
        a[0][mi] = *(const f16x8*)(p + q0);                                 \
        a[1][mi] = *(const f16x8*)(p + q1); } }

#define RD_B(S, nh)                                                         \
    { _Pragma("unroll") for (int ni = 0; ni < 2; ++ni) {                    \
        const f16* p = (S) + (((nh) * 2 + ni) * 32 + brow) * 64;            \
        b[0][(nh) * 2 + ni] = *(const f16x8*)(p + q0);                      \
        b[1][(nh) * 2 + ni] = *(const f16x8*)(p + q1); } }

#define QUAD(mh, nh)                                                        \
    { _Pragma("unroll") for (int mi = 0; mi < 2; ++mi)                      \
      _Pragma("unroll") for (int ni = 0; ni < 2; ++ni) {                    \
          f32x4& c = acc[(mh) * 2 + mi][(nh) * 2 + ni];                     \
          c = __builtin_amdgcn_mfma_f32_16x16x32_f16(a[0][mi], b[0][(nh) * 2 + ni], c, 0, 0, 0); \
          c = __builtin_amdgcn_mfma_f32_16x16x32_f16(a[1][mi], b[1][(nh) * 2 + ni], c, 0, 0, 0); \
      } }

#define QUAD2(mh)                                                           \
    { __builtin_amdgcn_s_setprio(1); QUAD(mh, 0); QUAD(mh, 1);              \
      __builtin_amdgcn_s_setprio(0); }

template <typename OT>
__global__ __launch_bounds__(256, 2) void gemm128(const f16* __restrict__ A,
                                                  const f16* __restrict__ B,
                                                  OT* __restrict__ C,
                                                  int M, int N, int K) {
    __shared__ __align__(16) f16 smem[4 * 8192];    // 64 KiB: A0|A1|B0|B1
    f16* const sA0 = smem;
    f16* const sA1 = smem + 8192;
    f16* const sB0 = smem + 16384;
    f16* const sB1 = smem + 24576;

    const int t = threadIdx.x;
    const int lane = t & 63;
    const int w = t >> 6;
    const int wr = w >> 1;                // 0..1 (M)
    const int wc = w & 1;                 // 0..1 (N)
    const int frow = lane & 15;
    const int fc = lane >> 4;

    // XCD-aware bijective swizzle (grid size is a multiple of 8)
    const int nbx = N >> 7;
    const int nwg = gridDim.x;
    const int wg = (blockIdx.x & 7) * (nwg >> 3) + (blockIdx.x >> 3);
    const int bm = (wg / nbx) << 7;
    const int bn = (wg % nbx) << 7;

    const int arow = wr * 16 + frow;      // + mh*64 + mi*32 (interleaved rows)
    const int brow = wc * 16 + frow;      // + (nh*2+ni)*32
    const int q0 = (fc ^ (frow & 7)) * 8;        // swizzled chunk, kstep 0
    const int q1 = ((4 + fc) ^ (frow & 7)) * 8;  // swizzled chunk, kstep 1

    f32x4 acc[4][4] = {};
    f16x8 a[2][2], b[2][4];

    // prologue: stage K-tiles 0 (buf0) and 1 (buf1)
    stage64(A, bm,      K, 0,  sA0);
    stage64(A, bm + 64, K, 0,  sA0 + 4096);
    stage64(B, bn,      K, 0,  sB0);
    stage64(B, bn + 64, K, 0,  sB0 + 4096);
    stage64(A, bm,      K, 64, sA1);
    stage64(A, bm + 64, K, 64, sA1 + 4096);
    stage64(B, bn,      K, 64, sB1);
    stage64(B, bn + 64, K, 64, sB1 + 4096);
    VM8;                                   // K-tile 0 landed (tile 1 in flight)
    BAR;

    const int NT = K >> 7;                 // 2 K-tiles (of 64) per iteration
    for (int it = 0; it < NT; ++it) {
        const bool lastit = (it == NT - 1);
        const int kc1 = (it * 2 + 1) << 6;
        const int kc2 = (it * 2 + 2) << 6;
        const int kc3 = (it * 2 + 3) << 6;

        // phA: consume buf0-h0 rows x all B of buf0; restage A1-h1 (tile 2it+1)
        RD_A(sA0, 0); RD_B(sB0, 0); RD_B(sB0, 1);
        if (it > 0) stage64(A, bm + 64, K, kc1, sA1 + 4096);
        BAR; QUAD2(0); BAR;

        // phB: consume buf0-h1 rows; restage buf0 (tile 2it+2) except A-h1
        RD_A(sA0, 1);
        if (!lastit) {
            stage64(A, bm,      K, kc2, sA0);
            stage64(B, bn,      K, kc2, sB0);
            stage64(B, bn + 64, K, kc2, sB0 + 4096);
            VM6;                           // tile 2it+1 fully landed
        } else {
            VM0;
        }
        BAR; QUAD2(1); BAR;

        // phC: consume buf1-h0 rows x all B of buf1; restage A0-h1 (kc2)
        RD_A(sA1, 0); RD_B(sB1, 0); RD_B(sB1, 1);
        if (!lastit) stage64(A, bm + 64, K, kc2, sA0 + 4096);
        BAR; QUAD2(0); BAR;

        // phD: consume buf1-h1 rows; restage buf1 (tile 2it+3) except A-h1
        RD_A(sA1, 1);
        if (!lastit) {
            stage64(A, bm,      K, kc3, sA1);
            stage64(B, bn,      K, kc3, sB1);
            stage64(B, bn + 64, K, kc3, sB1 + 4096);
            VM6;                           // tile 2it+2 fully landed
        }
        BAR; QUAD2(1); BAR;
    }

    // epilogue: C/D layout col = lane&15, row = (lane>>4)*4 + reg
    const size_t rb = (size_t)bm + wr * 16 + ((lane >> 4) << 2);
    const int cb = bn + wc * 16 + (lane & 15);
    #pragma unroll
    for (int m = 0; m < 4; ++m)
        #pragma unroll
        for (int n = 0; n < 4; ++n)
            #pragma unroll
            for (int rr = 0; rr < 4; ++rr)
                C[(rb + (m >> 1) * 64 + (m & 1) * 32 + rr) * N + cb + n * 32] =
                    (OT)acc[m][n][rr];
}

// ---------------------------------------------------------------------------
// Windowed attention, all-fp16 I/O, 4 rows per wave, ALL 32 k/v gathers
// issued up-front (v-load addresses depend only on seg, not on scores —
// doubling memory-level parallelism removes the second latency stall).
// Masked slots load zeros; their softmax weight is exp(-1e30)=0, so the
// accumulate needs no guard. Block = 4 waves = 4 head-groups; block b
// handles rows 4b..4b+3. lane = 16*hh + s; lane owns dims [4s,4s+4).
// ---------------------------------------------------------------------------
__global__ __launch_bounds__(256) void attn_kernel(const f16* __restrict__ qh,   // (B*LQ, 1024) fp16
                                                   const f16* __restrict__ kvp,  // (B*LKV, 2048): K|V fp16
                                                   const int* __restrict__ seg_id, // (B*LQ)
                                                   f16* __restrict__ attn_o) {     // (B*LQ, 1024) fp16
    const int hg = threadIdx.x >> 6;
    const int lane = threadIdx.x & 63;
    const int r0 = blockIdx.x << 2;      // 4 consecutive rows (same batch: LQ=4096)
    const int hh = lane >> 4;
    const int s  = lane & 15;
    const int dbase = (hg * 4 + hh) * HDIM + 4 * s;
    const int b = r0 >> 12;
    const f16* kvb = kvp + (size_t)b * LKV_C * (2 * D_ATTN);

    int seg[4];
    f16x4 qv[4];
    #pragma unroll
    for (int i = 0; i < 4; ++i) {
        seg[i] = seg_id[r0 + i];
        qv[i] = *(const f16x4*)(qh + (size_t)(r0 + i) * D_ATTN + dbase);
    }

    // issue ALL gathers (16 k + 16 v) before any use — 32 outstanding loads
    f16x4 kk[4][KW], vv[4][KW];
    #pragma unroll
    for (int i = 0; i < 4; ++i)
        #pragma unroll
        for (int w = 0; w < KW; ++w) {
            const int j = seg[i] - w;
            if (j >= 0) {
                const f16* base = kvb + (size_t)j * (2 * D_ATTN);
                kk[i][w] = *(const f16x4*)(base + dbase);
                vv[i][w] = *(const f16x4*)(base + D_ATTN + dbase);
            } else {
                kk[i][w] = (f16x4){0, 0, 0, 0};
                vv[i][w] = (f16x4){0, 0, 0, 0};
            }
        }

    // partial dots + butterflies
    float sc[4][KW];
    #pragma unroll
    for (int i = 0; i < 4; ++i)
        #pragma unroll
        for (int w = 0; w < KW; ++w)
            sc[i][w] = dot4_f16(qv[i], kk[i][w]);
    #pragma unroll
    for (int i = 0; i < 4; ++i)
        #pragma unroll
        for (int w = 0; w < KW; ++w) {
            float p = sc[i][w];
            p += __shfl_xor(p, 1);
            p += __shfl_xor(p, 2);
            p += __shfl_xor(p, 4);
            p += __shfl_xor(p, 8);
            sc[i][w] = (seg[i] - w >= 0) ? p * ATT_SCALE : -1e30f;
        }

    // softmax + weighted V accumulate (vv already in registers)
    #pragma unroll
    for (int i = 0; i < 4; ++i) {
        const float m = fmaxf(fmaxf(sc[i][0], sc[i][1]), fmaxf(sc[i][2], sc[i][3]));
        float e[KW], sum = 0.f;
        #pragma unroll
        for (int w = 0; w < KW; ++w) {
            e[w] = __expf(sc[i][w] - m);
            sum += e[w];
        }
        const float inv = 1.f / sum;

        float ox = 0.f, oy = 0.f, oz = 0.f, ow = 0.f;
        #pragma unroll
        for (int w = 0; w < KW; ++w) {
            const float c = e[w] * inv;
            ox = fmaf(c, (float)vv[i][w].x, ox);
            oy = fmaf(c, (float)vv[i][w].y, oy);
            oz = fmaf(c, (float)vv[i][w].z, oz);
            ow = fmaf(c, (float)vv[i][w].w, ow);
        }
        *(f16x4*)(attn_o + (size_t)(r0 + i) * D_ATTN + dbase) =
            (f16x4){(f16)ox, (f16)oy, (f16)oz, (f16)ow};
    }
}

extern "C" void kernel_launch(void* const* d_in, const int* in_sizes, int n_in,
                              void* d_out, int out_size, void* d_ws, size_t ws_size,
                              hipStream_t stream) {
    const float* q      = (const float*)d_in[0]; // (4,4096,1024)
    const float* kv_src = (const float*)d_in[1]; // (4,512,1024)
    const int*   seg    = (const int*)  d_in[2]; // (4,4096)
    const float* Wq     = (const float*)d_in[3]; // (1024,1024)
    const float* Wkv    = (const float*)d_in[4]; // (2048,1024)
    const float* Wo     = (const float*)d_in[5]; // (1024,1024)
    float* out = (float*)d_out;

    const int M  = B_C * LQ_C;    // 16384
    const int Mk = B_C * LKV_C;   // 2048

    // workspace layout (~52 MB)
    f16* q_hi   = (f16*)d_ws;                       // 32 MB
    f16* kvs_hi = q_hi   + (size_t)M * D_ATTN;      // 4 MB
    f16* Wq_hi  = kvs_hi + (size_t)Mk * 1024;       // 2 MB
    f16* Wkv_hi = Wq_hi  + 1024 * 1024;             // 4 MB
    f16* Wo_hi  = Wkv_hi + 2048 * 1024;             // 2 MB
    f16* kvp    = Wo_hi  + 1024 * 1024;             // 8 MB (fp16 K|V)
    f16* attn_o = q_hi;             // alias: q_hi dead after GEMM1
    f16* qh16   = (f16*)d_out;      // qh (fp16) parked in d_out, overwritten by GEMM3

    // 1. fp32 -> fp16 conversion of all inputs (single kernel)
    split_all<<<SEG_END / 256, 256, 0, stream>>>(q, kv_src, Wq, Wkv, Wo,
                                                 q_hi, kvs_hi, Wq_hi, Wkv_hi, Wo_hi);

    // 2. kvp = kv_src @ Wkv^T  (fp16)
    gemm_f16<f16><<<dim3(2048 / 128, Mk / 128), 256, 0, stream>>>(kvs_hi, Wkv_hi, kvp, Mk, 2048, 1024);
    // 3. qh16 = q @ Wq^T  (fp16, into d_out)
    gemm128<f16><<<(M / 128) * (1024 / 128), 256, 0, stream>>>(q_hi, Wq_hi, qh16, M, 1024, 1024);
    // 4. windowed attention -> fp16 attn (aliases q_hi)
    attn_kernel<<<M / 4, 256, 0, stream>>>(qh16, kvp, seg, attn_o);
    // 5. out = attn @ Wo^T  (fp32, overwrites d_out)
    gemm128<float><<<(M / 128) * (1024 / 128), 256, 0, stream>>>(attn_o, Wo_hi, out, M, 1024, 1024);
}

// Round 8
// 255.397 us; speedup vs baseline: 1.0764x; 1.0150x over previous
//
#include <hip/hip_runtime.h>
#include <math.h>

#define NH 16
#define HDIM 64
#define D_ATTN 1024
#define KW 4
#define ATT_SCALE 0.125f
#define LKV_C 512
#define LQ_C 4096
#define B_C 4

typedef _Float16 f16;
typedef _Float16 f16x8 __attribute__((ext_vector_type(8)));
typedef _Float16 f16x4 __attribute__((ext_vector_type(4)));
typedef _Float16 f16x2 __attribute__((ext_vector_type(2)));
typedef float f32x4 __attribute__((ext_vector_type(4)));

typedef __attribute__((address_space(3))) unsigned int as3_uint;
typedef __attribute__((address_space(1))) const unsigned int as1_uint;

__device__ __forceinline__ void gld_lds16(const f16* g, f16* l) {
    __builtin_amdgcn_global_load_lds((as1_uint*)g, (as3_uint*)l, 16, 0, 0);
}

// fp16 4-element dot with fp32 accumulate (v_dot2_f32_f16 when available)
__device__ __forceinline__ float dot4_f16(f16x4 a, f16x4 b) {
#if __has_builtin(__builtin_amdgcn_fdot2)
    f16x2 alo = {a.x, a.y}, ahi = {a.z, a.w};
    f16x2 blo = {b.x, b.y}, bhi = {b.z, b.w};
    float p = __builtin_amdgcn_fdot2(alo, blo, 0.f, false);
    return __builtin_amdgcn_fdot2(ahi, bhi, p, false);
#else
    return (float)a.x * (float)b.x + (float)a.y * (float)b.y +
           (float)a.z * (float)b.z + (float)a.w * (float)b.w;
#endif
}

// ---------------------------------------------------------------------------
// One-shot fp32 -> fp16 conversion of all five inputs.
// ---------------------------------------------------------------------------
#define SEG_Q   4194304          // 4*4096*1024/4
#define SEG_KV  (SEG_Q + 524288) // + 4*512*1024/4
#define SEG_WQ  (SEG_KV + 262144)
#define SEG_WKV (SEG_WQ + 524288)
#define SEG_END (SEG_WKV + 262144)

__global__ __launch_bounds__(256) void split_all(const float* __restrict__ q,
                                                 const float* __restrict__ kv,
                                                 const float* __restrict__ Wq,
                                                 const float* __restrict__ Wkv,
                                                 const float* __restrict__ Wo,
                                                 f16* __restrict__ q_hi,
                                                 f16* __restrict__ kvs_hi,
                                                 f16* __restrict__ Wq_hi,
                                                 f16* __restrict__ Wkv_hi,
                                                 f16* __restrict__ Wo_hi) {
    const int i = blockIdx.x * 256 + threadIdx.x;
    const float* src; f16* dst; int base;
    if (i < SEG_Q)        { src = q;   dst = q_hi;   base = 0; }
    else if (i < SEG_KV)  { src = kv;  dst = kvs_hi; base = SEG_Q; }
    else if (i < SEG_WQ)  { src = Wq;  dst = Wq_hi;  base = SEG_KV; }
    else if (i < SEG_WKV) { src = Wkv; dst = Wkv_hi; base = SEG_WQ; }
    else                  { src = Wo;  dst = Wo_hi;  base = SEG_WKV; }
    const int j = i - base;
    float4 v = ((const float4*)src)[j];
    ((f16x4*)dst)[j] = (f16x4){(f16)v.x, (f16)v.y, (f16)v.z, (f16)v.w};
}

// ---------------------------------------------------------------------------
// 128x128-tile GEMM (2-barrier structure) — kept for the kv projection
// (M=2048, N=2048: 256 blocks). Templated output type (fp32 or fp16).
// ---------------------------------------------------------------------------
template <typename OT>
__global__ __launch_bounds__(256) void gemm_f16(const f16* __restrict__ A,
                                                const f16* __restrict__ B,
                                                OT* __restrict__ C,
                                                int M, int N, int K) {
    __shared__ f16 smem[2 * 128 * 32];   // A | B, 16 KB
    f16* sA = smem;
    f16* sB = smem + 4096;

    const int t = threadIdx.x;
    const int w = t >> 6;
    const int lane = t & 63;
    const int bm = blockIdx.y * 128;
    const int bn = blockIdx.x * 128;
    const int wm = (w & 1) * 64;
    const int wn = (w >> 1) * 64;

    f32x4 acc[4][4] = {};

    const int frow = lane & 15;
    const int fchunk = lane >> 4;

    const int srow = t >> 2;
    const int chunk = (t & 3) ^ ((t >> 3) & 3);
    const size_t aoff0 = (size_t)(bm + srow) * K + chunk * 8;
    const size_t aoff1 = (size_t)(bm + 64 + srow) * K + chunk * 8;
    const size_t boff0 = (size_t)(bn + srow) * K + chunk * 8;
    const size_t boff1 = (size_t)(bn + 64 + srow) * K + chunk * 8;
    const unsigned loff0 = (w * 64) * 8;
    const unsigned loff1 = (256 + w * 64) * 8;

    gld_lds16(A + aoff0, sA + loff0);  gld_lds16(A + aoff1, sA + loff1);
    gld_lds16(B + boff0, sB + loff0);  gld_lds16(B + boff1, sB + loff1);

    for (int k0 = 0; k0 < K; k0 += 32) {
        __syncthreads();

        f16x8 a[4], b[4];
        #pragma unroll
        for (int i = 0; i < 4; ++i) {
            const int r = wm + i * 16 + frow;
            a[i] = *(const f16x8*)(sA + r * 32 + (fchunk ^ ((r >> 1) & 3)) * 8);
        }
        #pragma unroll
        for (int j = 0; j < 4; ++j) {
            const int r = wn + j * 16 + frow;
            b[j] = *(const f16x8*)(sB + r * 32 + (fchunk ^ ((r >> 1) & 3)) * 8);
        }

        __syncthreads();

        if (k0 + 32 < K) {
            const int kn = k0 + 32;
            gld_lds16(A + aoff0 + kn, sA + loff0);  gld_lds16(A + aoff1 + kn, sA + loff1);
            gld_lds16(B + boff0 + kn, sB + loff0);  gld_lds16(B + boff1 + kn, sB + loff1);
        }

        #pragma unroll
        for (int i = 0; i < 4; ++i)
            #pragma unroll
            for (int j = 0; j < 4; ++j)
                acc[i][j] = __builtin_amdgcn_mfma_f32_16x16x32_f16(a[i], b[j], acc[i][j], 0, 0, 0);
    }

    const int rbase = bm + wm + (lane >> 4) * 4;
    const int cbase = bn + wn + (lane & 15);
    #pragma unroll
    for (int i = 0; i < 4; ++i)
        #pragma unroll
        for (int j = 0; j < 4; ++j)
            #pragma unroll
            for (int r = 0; r < 4; ++r)
                C[(size_t)(rbase + i * 16 + r) * N + cbase + j * 16] = (OT)acc[i][j][r];
}

// ---------------------------------------------------------------------------
// 128x128-tile, BK=64, 4-phase, counted-vmcnt GEMM — 8 waves (512 threads).
// Same phase schedule as round 4, but 2x the waves/SIMD (4 instead of 2) at
// unchanged 64 KiB LDS / 2 blocks/CU: MfmaUtil 33% showed each SIMD's 2
// waves were jointly stalled ~60% of cycles; 4 waves/SIMD doubles stall
// coverage. Waves 2M x 4N; wave owns 64 rows x 32 cols (interleaved rows:
// row = mh*64 + mi*32 + wr*16 + frow, col = ni*64 + wc*16 + fcol — all
// offsets are multiples of 8 so the XOR chunk swizzle index (frow&7) is
// unchanged). Staging: 512 threads -> 1 load/thread per stage64w, so vmcnt
// constants halve vs round 4:
//   prologue: 8 loads in flight, VM4 -> K-tile 0 (oldest 4) landed
//   phA: reads {A0h0,B0h0,B0h1}; restage A1h1 (tile 2it+1)  [+1 load]
//   phB: reads {A0h1}; restage A0h0,B0h0,B0h1 @kc2 [+3], VM3 -> in-flight
//        before wait = 3(phD prev)+1(phA)+3(phB) = 7, drains 4 oldest
//        = all of tile 2it+1 (consumed in phC/phD)
//   phC: reads {A1h0,B1h0,B1h1}; restage A0h1 @kc2 [+1]
//   phD: reads {A1h1}; restage A1h0,B1h0,B1h1 @kc3 [+3], VM3 -> drains
//        tile 2it+2 (consumed next phA/phB)
// B fragments are read once per K-tile (phA/phC) and reused in phB/phD.
// Requires M%128==0, N%128==0, K%128==0, grid%8==0.
// ---------------------------------------------------------------------------
__device__ __forceinline__ void stage64w(const f16* __restrict__ g, size_t row0,
                                         int K, int kcol, f16* l) {
    const int idx = threadIdx.x;                 // 512 x 16B = 64 rows x 64 cols
    const int r = idx >> 3;
    const int qg = (idx & 7) ^ (r & 7);          // inverse (= same) swizzle
    gld_lds16(g + (row0 + r) * (size_t)K + kcol + qg * 8, l + idx * 8);
}

#define BAR __builtin_amdgcn_s_barrier()
#define VM3 asm volatile("s_waitcnt vmcnt(3)" ::: "memory")
#define VM4 asm volatile("s_waitcnt vmcnt(4)" ::: "memory")
#define VM0 asm volatile("s_waitcnt vmcnt(0)" ::: "memory")

#define RD_A8(S, mh)                                                        \
    { _Pragma("unroll") for (int mi = 0; mi < 2; ++mi) {                    \
        const f16* p = (S) + ((mh) * 64 + mi * 32 + arow) * 64;             \
        a[0][mi] = *(const f16x8*)(p + q0);                                 \
        a[1][mi] = *(const f16x8*)(p + q1); } }

#define RD_B8(S)                                                            \
    { _Pragma("unroll") for (int ni = 0; ni < 2; ++ni) {                    \
        const f16* p = (S) + (ni * 64 + brow) * 64;                         \
        b[0][ni] = *(const f16x8*)(p + q0);                                 \
        b[1][ni] = *(const f16x8*)(p + q1); } }

#define QUAD8(mh)                                                           \
    { __builtin_amdgcn_s_setprio(1);                                        \
      _Pragma("unroll") for (int mi = 0; mi < 2; ++mi)                      \
      _Pragma("unroll") for (int ni = 0; ni < 2; ++ni) {                    \
          f32x4& c = acc[(mh) * 2 + mi][ni];                                \
          c = __builtin_amdgcn_mfma_f32_16x16x32_f16(a[0][mi], b[0][ni], c, 0, 0, 0); \
          c = __builtin_amdgcn_mfma_f32_16x16x32_f16(a[1][mi], b[1][ni], c, 0, 0, 0); \
      }                                                                     \
      __builtin_amdgcn_s_setprio(0); }

template <typename OT>
__global__ __launch_bounds__(512, 4) void gemm128x8(const f16* __restrict__ A,
                                                    const f16* __restrict__ B,
                                                    OT* __restrict__ C,
                                                    int M, int N, int K) {
    __shared__ __align__(16) f16 smem[4 * 8192];    // 64 KiB: A0|A1|B0|B1
    f16* const sA0 = smem;
    f16* const sA1 = smem + 8192;
    f16* const sB0 = smem + 16384;
    f16* const sB1 = smem + 24576;

    const int t = threadIdx.x;
    const int lane = t & 63;
    const int w = t >> 6;                 // 0..7
    const int wr = w >> 2;                // 0..1 (M)
    const int wc = w & 3;                 // 0..3 (N)
    const int frow = lane & 15;
    const int fc = lane >> 4;

    // XCD-aware bijective swizzle (grid size is a multiple of 8)
    const int nbx = N >> 7;
    const int nwg = gridDim.x;
    const int wg = (blockIdx.x & 7) * (nwg >> 3) + (blockIdx.x >> 3);
    const int bm = (wg / nbx) << 7;
    const int bn = (wg % nbx) << 7;

    const int arow = wr * 16 + frow;      // + mh*64 + mi*32 (interleaved rows)
    const int brow = wc * 16 + frow;      // + ni*64
    const int q0 = (fc ^ (frow & 7)) * 8;        // swizzled chunk, kstep 0
    const int q1 = ((4 + fc) ^ (frow & 7)) * 8;  // swizzled chunk, kstep 1

    f32x4 acc[4][2] = {};
    f16x8 a[2][2], b[2][2];

    // prologue: stage K-tiles 0 (buf0) and 1 (buf1); 8 loads/thread in flight
    stage64w(A, bm,      K, 0,  sA0);
    stage64w(A, bm + 64, K, 0,  sA0 + 4096);
    stage64w(B, bn,      K, 0,  sB0);
    stage64w(B, bn + 64, K, 0,  sB0 + 4096);
    stage64w(A, bm,      K, 64, sA1);
    stage64w(A, bm + 64, K, 64, sA1 + 4096);
    stage64w(B, bn,      K, 64, sB1);
    stage64w(B, bn + 64, K, 64, sB1 + 4096);
    VM4;                                   // K-tile 0 landed (tile 1 in flight)
    BAR;

    const int NT = K >> 7;                 // 2 K-tiles (of 64) per iteration
    for (int it = 0; it < NT; ++it) {
        const bool lastit = (it == NT - 1);
        const int kc1 = (it * 2 + 1) << 6;
        const int kc2 = (it * 2 + 2) << 6;
        const int kc3 = (it * 2 + 3) << 6;

        // phA: read A0-h0 + all B0; restage A1-h1 (tile 2it+1)
        RD_A8(sA0, 0); RD_B8(sB0);
        if (it > 0) stage64w(A, bm + 64, K, kc1, sA1 + 4096);
        BAR; QUAD8(0); BAR;

        // phB: read A0-h1 (B regs persist); restage tile 2it+2 except A-h1
        RD_A8(sA0, 1);
        if (!lastit) {
            stage64w(A, bm,      K, kc2, sA0);
            stage64w(B, bn,      K, kc2, sB0);
            stage64w(B, bn + 64, K, kc2, sB0 + 4096);
            VM3;                           // tile 2it+1 fully landed
        } else {
            VM0;
        }
        BAR; QUAD8(1); BAR;

        // phC: read A1-h0 + all B1; restage A0-h1 @kc2
        RD_A8(sA1, 0); RD_B8(sB1);
        if (!lastit) stage64w(A, bm + 64, K, kc2, sA0 + 4096);
        BAR; QUAD8(0); BAR;

        // phD: read A1-h1; restage tile 2it+3 except A-h1
        RD_A8(sA1, 1);
        if (!lastit) {
            stage64w(A, bm,      K, kc3, sA1);
            stage64w(B, bn,      K, kc3, sB1);
            stage64w(B, bn + 64, K, kc3, sB1 + 4096);
            VM3;                           // tile 2it+2 fully landed
        }
        BAR; QUAD8(1); BAR;
    }

    // epilogue: C/D layout col = lane&15, row = (lane>>4)*4 + reg
    const size_t rb = (size_t)bm + wr * 16 + ((lane >> 4) << 2);
    const int cb = bn + wc * 16 + (lane & 15);
    #pragma unroll
    for (int m = 0; m < 4; ++m)
        #pragma unroll
        for (int n = 0; n < 2; ++n)
            #pragma unroll
            for (int rr = 0; rr < 4; ++rr)
                C[(rb + (m >> 1) * 64 + (m & 1) * 32 + rr) * N + cb + n * 64] =
                    (OT)acc[m][n][rr];
}

// ---------------------------------------------------------------------------
// Windowed attention, all-fp16 I/O, 4 rows per wave, ALL 32 k/v gathers
// issued up-front (v-load addresses depend only on seg). Unchanged from
// round 6 (dropped out of top-5).
// ---------------------------------------------------------------------------
__global__ __launch_bounds__(256) void attn_kernel(const f16* __restrict__ qh,
                                                   const f16* __restrict__ kvp,
                                                   const int* __restrict__ seg_id,
                                                   f16* __restrict__ attn_o) {
    const int hg = threadIdx.x >> 6;
    const int lane = threadIdx.x & 63;
    const int r0 = blockIdx.x << 2;
    const int hh = lane >> 4;
    const int s  = lane & 15;
    const int dbase = (hg * 4 + hh) * HDIM + 4 * s;
    const int b = r0 >> 12;
    const f16* kvb = kvp + (size_t)b * LKV_C * (2 * D_ATTN);

    int seg[4];
    f16x4 qv[4];
    #pragma unroll
    for (int i = 0; i < 4; ++i) {
        seg[i] = seg_id[r0 + i];
        qv[i] = *(const f16x4*)(qh + (size_t)(r0 + i) * D_ATTN + dbase);
    }

    f16x4 kk[4][KW], vv[4][KW];
    #pragma unroll
    for (int i = 0; i < 4; ++i)
        #pragma unroll
        for (int w = 0; w < KW; ++w) {
            const int j = seg[i] - w;
            if (j >= 0) {
                const f16* base = kvb + (size_t)j * (2 * D_ATTN);
                kk[i][w] = *(const f16x4*)(base + dbase);
                vv[i][w] = *(const f16x4*)(base + D_ATTN + dbase);
            } else {
                kk[i][w] = (f16x4){0, 0, 0, 0};
                vv[i][w] = (f16x4){0, 0, 0, 0};
            }
        }

    float sc[4][KW];
    #pragma unroll
    for (int i = 0; i < 4; ++i)
        #pragma unroll
        for (int w = 0; w < KW; ++w)
            sc[i][w] = dot4_f16(qv[i], kk[i][w]);
    #pragma unroll
    for (int i = 0; i < 4; ++i)
        #pragma unroll
        for (int w = 0; w < KW; ++w) {
            float p = sc[i][w];
            p += __shfl_xor(p, 1);
            p += __shfl_xor(p, 2);
            p += __shfl_xor(p, 4);
            p += __shfl_xor(p, 8);
            sc[i][w] = (seg[i] - w >= 0) ? p * ATT_SCALE : -1e30f;
        }

    #pragma unroll
    for (int i = 0; i < 4; ++i) {
        const float m = fmaxf(fmaxf(sc[i][0], sc[i][1]), fmaxf(sc[i][2], sc[i][3]));
        float e[KW], sum = 0.f;
        #pragma unroll
        for (int w = 0; w < KW; ++w) {
            e[w] = __expf(sc[i][w] - m);
            sum += e[w];
        }
        const float inv = 1.f / sum;

        float ox = 0.f, oy = 0.f, oz = 0.f, ow = 0.f;
        #pragma unroll
        for (int w = 0; w < KW; ++w) {
            const float c = e[w] * inv;
            ox = fmaf(c, (float)vv[i][w].x, ox);
            oy = fmaf(c, (float)vv[i][w].y, oy);
            oz = fmaf(c, (float)vv[i][w].z, oz);
            ow = fmaf(c, (float)vv[i][w].w, ow);
        }
        *(f16x4*)(attn_o + (size_t)(r0 + i) * D_ATTN + dbase) =
            (f16x4){(f16)ox, (f16)oy, (f16)oz, (f16)ow};
    }
}

extern "C" void kernel_launch(void* const* d_in, const int* in_sizes, int n_in,
                              void* d_out, int out_size, void* d_ws, size_t ws_size,
                              hipStream_t stream) {
    const float* q      = (const float*)d_in[0]; // (4,4096,1024)
    const float* kv_src = (const float*)d_in[1]; // (4,512,1024)
    const int*   seg    = (const int*)  d_in[2]; // (4,4096)
    const float* Wq     = (const float*)d_in[3]; // (1024,1024)
    const float* Wkv    = (const float*)d_in[4]; // (2048,1024)
    const float* Wo     = (const float*)d_in[5]; // (1024,1024)
    float* out = (float*)d_out;

    const int M  = B_C * LQ_C;    // 16384
    const int Mk = B_C * LKV_C;   // 2048

    // workspace layout (~52 MB)
    f16* q_hi   = (f16*)d_ws;                       // 32 MB
    f16* kvs_hi = q_hi   + (size_t)M * D_ATTN;      // 4 MB
    f16* Wq_hi  = kvs_hi + (size_t)Mk * 1024;       // 2 MB
    f16* Wkv_hi = Wq_hi  + 1024 * 1024;             // 4 MB
    f16* Wo_hi  = Wkv_hi + 2048 * 1024;             // 2 MB
    f16* kvp    = Wo_hi  + 1024 * 1024;             // 8 MB (fp16 K|V)
    f16* attn_o = q_hi;             // alias: q_hi dead after GEMM1
    f16* qh16   = (f16*)d_out;      // qh (fp16) parked in d_out, overwritten by GEMM3

    // 1. fp32 -> fp16 conversion of all inputs (single kernel)
    split_all<<<SEG_END / 256, 256, 0, stream>>>(q, kv_src, Wq, Wkv, Wo,
                                                 q_hi, kvs_hi, Wq_hi, Wkv_hi, Wo_hi);

    // 2. kvp = kv_src @ Wkv^T  (fp16)
    gemm_f16<f16><<<dim3(2048 / 128, Mk / 128), 256, 0, stream>>>(kvs_hi, Wkv_hi, kvp, Mk, 2048, 1024);
    // 3. qh16 = q @ Wq^T  (fp16, into d_out) — 8-wave 128^2, 4 waves/SIMD
    gemm128x8<f16><<<(M / 128) * (1024 / 128), 512, 0, stream>>>(q_hi, Wq_hi, qh16, M, 1024, 1024);
    // 4. windowed attention -> fp16 attn (aliases q_hi)
    attn_kernel<<<M / 4, 256, 0, stream>>>(qh16, kvp, seg, attn_o);
    // 5. out = attn @ Wo^T  (fp32, overwrites d_out)
    gemm128x8<float><<<(M / 128) * (1024 / 128), 512, 0, stream>>>(attn_o, Wo_hi, out, M, 1024, 1024);
}